// Round 1
// baseline (274.122 us; speedup 1.0000x reference)
//
#include <hip/hip_runtime.h>
#include <hip/hip_bf16.h>

typedef unsigned short u16;
typedef unsigned int u32;
typedef __attribute__((ext_vector_type(4))) float f32x4;
typedef __attribute__((ext_vector_type(8))) short bf16x8;

#define DD 1024
#define BSZ 32
#define MROWS 1024
#define K3 3072
#define SPLITK 4
#define KSPLIT 768
#define BMT 128
#define BKT 64

static __device__ __forceinline__ u16 bf16rne(float f) {
    union { float f; u32 u; } a; a.f = f;
    u32 r = a.u + 0x7fffu + ((a.u >> 16) & 1u);
    return (u16)(r >> 16);
}
static __device__ __forceinline__ u32 packbf2(float a, float b) {
    return (u32)bf16rne(a) | ((u32)bf16rne(b) << 16);
}

// ---------------- kernel 1: per-32-row-block stats -> feat [1024][3072] bf16 ----------------
// grid 1024 (one per block-of-32-rows), 512 threads; each thread owns 2 columns, keeps
// the 32x2 slab in registers (f32 precision end-to-end; only feat output is bf16).
__global__ void k_blockstats(const float* __restrict__ x, const float* __restrict__ w_w,
                             const float* __restrict__ w_b, u16* __restrict__ feat) {
    const int m = blockIdx.x;          // = b*256 + n
    const int t = threadIdx.x;         // 0..511, cols 2t,2t+1
    const int lane = t & 63, wv = t >> 6;
    __shared__ float lg[BSZ][8];
    __shared__ float wts[BSZ];
    const float2 wp = *(const float2*)(w_w + 2 * t);
    const float* xb = x + (size_t)m * BSZ * DD;
    float2 xs[BSZ];
#pragma unroll
    for (int r = 0; r < BSZ; ++r) {
        float2 v = *(const float2*)(xb + (size_t)r * DD + 2 * t);
        xs[r] = v;
        float d = v.x * wp.x + v.y * wp.y;
#pragma unroll
        for (int off = 32; off; off >>= 1) d += __shfl_xor(d, off);
        if (lane == 0) lg[r][wv] = d;
    }
    __syncthreads();
    if (t < BSZ) {                     // lanes 0..31 of wave 0: softmax over 32 logits
        float s = w_b[0];
#pragma unroll
        for (int w = 0; w < 8; ++w) s += lg[t][w];
        float mx = s;
#pragma unroll
        for (int off = 16; off; off >>= 1) mx = fmaxf(mx, __shfl_xor(mx, off, 32));
        float e = __expf(s - mx);
        float se = e;
#pragma unroll
        for (int off = 16; off; off >>= 1) se += __shfl_xor(se, off, 32);
        wts[t] = e / se;
    }
    __syncthreads();
    float wmx = 0.f, wmy = 0.f, m2x = 0.f, m2y = 0.f, mxx = -3.4e38f, mxy = -3.4e38f;
#pragma unroll
    for (int r = 0; r < BSZ; ++r) {
        float w = wts[r];
        float2 v = xs[r];
        wmx += w * v.x; wmy += w * v.y;
        m2x += w * v.x * v.x; m2y += w * v.y * v.y;
        mxx = fmaxf(mxx, v.x); mxy = fmaxf(mxy, v.y);
    }
    float sdx = sqrtf(fmaxf(m2x - wmx * wmx, 0.f) + 1e-8f);
    float sdy = sqrtf(fmaxf(m2y - wmy * wmy, 0.f) + 1e-8f);
    u32* fr = (u32*)(feat + (size_t)m * K3);   // [mn | sd | mx], 512 u32 each
    fr[t] = packbf2(wmx, wmy);
    fr[512 + t] = packbf2(sdx, sdy);
    fr[1024 + t] = packbf2(mxx, mxy);
}

// ---------------- kernel 2: proj_w [3072][1024] f32 -> Bt [1024][3072] bf16 ----------------
__global__ void k_transpose(const float* __restrict__ pw, u16* __restrict__ bt) {
    __shared__ float tile[64][33];
    const int bk = blockIdx.x;   // 0..47 over K3/64
    const int bn = blockIdx.y;   // 0..31 over DD/32
    const int t = threadIdx.x;   // 256
    const int c = t & 31;
    const int r0 = t >> 5;
#pragma unroll
    for (int p = 0; p < 8; ++p) {
        int r = r0 + p * 8;
        tile[r][c] = pw[(size_t)(bk * 64 + r) * DD + bn * 32 + c];
    }
    __syncthreads();
#pragma unroll
    for (int p = 0; p < 4; ++p) {
        int rr = r0 + p * 8;     // output row (n), 0..31
        u32 u = packbf2(tile[2 * c][rr], tile[2 * c + 1][rr]);
        ((u32*)(bt + (size_t)(bn * 32 + rr) * K3 + bk * 64))[c] = u;
    }
}

// ---------------- kernel 3: C_partial[z] = feat[:, z*768:(z+1)*768] @ proj_w[...] ----------------
// 128x128 tile, BK=64, 4 waves x (64x64 via 4x4 16x16x32 frags), split-K=4,
// global_load_lds w=16, XOR-swizzled global source + swizzled LDS read (rule #21).
__global__ __launch_bounds__(256) void k_gemm(const u16* __restrict__ A, const u16* __restrict__ Bt,
                                              float* __restrict__ part) {
    __shared__ u16 As[2][BMT * BKT];
    __shared__ u16 Bs[2][BMT * BKT];
    const int t = threadIdx.x;
    const int m0 = blockIdx.x * BMT;
    const int n0 = blockIdx.y * BMT;
    const int z = blockIdx.z;
    const int k0 = z * KSPLIT;

    const int lane = t & 63;
    const int wv = t >> 6;
    const int wm = (wv >> 1) * 64;
    const int wn = (wv & 1) * 64;
    const int l15 = lane & 15;
    const int lh = lane >> 4;

    // staging map: slot = j*256+t -> LDS row slot>>3, col-byte (slot&7)*16 (linear dest);
    // global source column pre-XOR-swizzled so swizzled reads see A[row][c].
    const int srow = t >> 3;
    const int scb = (t & 7) * 16;
    const int gcb = scb ^ ((srow & 7) << 4);
    const u16* gAr = A + (size_t)(m0 + srow) * K3 + (gcb >> 1) + k0;
    const u16* gBr = Bt + (size_t)(n0 + srow) * K3 + (gcb >> 1) + k0;
    const int ldsBase = (t & ~63) * 8;   // wave-uniform LDS base (u16 elems), +j*2048 per call

    f32x4 acc[4][4] = {};

#define STAGE(buf, kEl)                                                                            \
    {                                                                                              \
        _Pragma("unroll") for (int j = 0; j < 4; ++j) {                                            \
            __builtin_amdgcn_global_load_lds(                                                      \
                (__attribute__((address_space(1))) void*)(gAr + (kEl) + (size_t)j * 32 * K3),      \
                (__attribute__((address_space(3))) void*)&As[buf][j * 2048 + ldsBase], 16, 0, 0);  \
            __builtin_amdgcn_global_load_lds(                                                      \
                (__attribute__((address_space(1))) void*)(gBr + (kEl) + (size_t)j * 32 * K3),      \
                (__attribute__((address_space(3))) void*)&Bs[buf][j * 2048 + ldsBase], 16, 0, 0);  \
        }                                                                                          \
    }
#define LDIDX(row, cb) ((((row)*128) + (((cb) ^ (((row)&7) << 4)))) >> 1)

    STAGE(0, 0)
    __syncthreads();
    int cur = 0;
    for (int it = 0; it < KSPLIT / BKT; ++it) {   // 12 iters
        if (it < KSPLIT / BKT - 1) STAGE(cur ^ 1, (it + 1) * BKT)
#pragma unroll
        for (int kk = 0; kk < 2; ++kk) {
            bf16x8 af[4], bfr[4];
            const int cb = kk * 64 + lh * 16;
#pragma unroll
            for (int mi = 0; mi < 4; ++mi)
                af[mi] = *(const bf16x8*)&As[cur][LDIDX(wm + mi * 16 + l15, cb)];
#pragma unroll
            for (int ni = 0; ni < 4; ++ni)
                bfr[ni] = *(const bf16x8*)&Bs[cur][LDIDX(wn + ni * 16 + l15, cb)];
#pragma unroll
            for (int mi = 0; mi < 4; ++mi)
#pragma unroll
                for (int ni = 0; ni < 4; ++ni)
                    acc[mi][ni] =
                        __builtin_amdgcn_mfma_f32_16x16x32_bf16(af[mi], bfr[ni], acc[mi][ni], 0, 0, 0);
        }
        __syncthreads();   // drains vmcnt (next-tile stage) + lgkm; 2-phase pipeline
        cur ^= 1;
    }

    // C/D map: col = lane&15, row = (lane>>4)*4 + reg  [measured m89/m91]
    float* pz = part + (size_t)z * MROWS * DD;
#pragma unroll
    for (int mi = 0; mi < 4; ++mi) {
#pragma unroll
        for (int r = 0; r < 4; ++r) {
            const int gm = m0 + wm + mi * 16 + lh * 4 + r;
            float* rp = pz + (size_t)gm * DD + n0 + wn + l15;
#pragma unroll
            for (int ni = 0; ni < 4; ++ni) rp[ni * 16] = acc[mi][ni][r];
        }
    }
#undef STAGE
#undef LDIDX
}

// ---------------- kernel 4: sum split-K partials + bias + LayerNorm + pos ----------------
__global__ void k_lnreduce(const float* __restrict__ part, const float* __restrict__ proj_b,
                           const float* __restrict__ ln_g, const float* __restrict__ ln_b,
                           const float* __restrict__ pos, float* __restrict__ out) {
    const int m = blockIdx.x;      // 0..1023
    const int t = threadIdx.x;     // 256
    const int c = 4 * t;
    const int lane = t & 63, wv = t >> 6;
    f32x4 h = {};
#pragma unroll
    for (int s = 0; s < SPLITK; ++s)
        h += *(const f32x4*)(part + ((size_t)s * MROWS + m) * DD + c);
    h += *(const f32x4*)(proj_b + c);
    float sm = h[0] + h[1] + h[2] + h[3];
    float sq = h[0] * h[0] + h[1] * h[1] + h[2] * h[2] + h[3] * h[3];
#pragma unroll
    for (int off = 32; off; off >>= 1) { sm += __shfl_xor(sm, off); sq += __shfl_xor(sq, off); }
    __shared__ float rs[4], rq[4];
    if (lane == 0) { rs[wv] = sm; rq[wv] = sq; }
    __syncthreads();
    const float S = rs[0] + rs[1] + rs[2] + rs[3];
    const float Q = rq[0] + rq[1] + rq[2] + rq[3];
    const float mu = S * (1.f / 1024.f);
    const float var = Q * (1.f / 1024.f) - mu * mu;
    const float rstd = rsqrtf(var + 1e-5f);
    const f32x4 g = *(const f32x4*)(ln_g + c);
    const f32x4 b = *(const f32x4*)(ln_b + c);
    const f32x4 p = *(const f32x4*)(pos + (size_t)(m & 255) * DD + c);
    f32x4 o;
#pragma unroll
    for (int i = 0; i < 4; ++i) o[i] = (h[i] - mu) * rstd * g[i] + b[i] + p[i];
    *(f32x4*)(out + (size_t)m * DD + c) = o;
}

extern "C" void kernel_launch(void* const* d_in, const int* in_sizes, int n_in,
                              void* d_out, int out_size, void* d_ws, size_t ws_size,
                              hipStream_t stream) {
    const float* x      = (const float*)d_in[0];
    const float* w_w    = (const float*)d_in[1];
    const float* w_b    = (const float*)d_in[2];
    const float* proj_w = (const float*)d_in[3];
    const float* proj_b = (const float*)d_in[4];
    const float* ln_g   = (const float*)d_in[5];
    const float* ln_b   = (const float*)d_in[6];
    const float* pos    = (const float*)d_in[7];
    float* out = (float*)d_out;

    char* ws = (char*)d_ws;
    u16* feat  = (u16*)ws;                      // 1024*3072*2 = 6 MiB
    u16* bt    = (u16*)(ws + 6291456);          // 1024*3072*2 = 6 MiB
    float* prt = (float*)(ws + 12582912);       // 4*1024*1024*4 = 16 MiB

    k_blockstats<<<1024, 512, 0, stream>>>(x, w_w, w_b, feat);
    k_transpose<<<dim3(48, 32), 256, 0, stream>>>(proj_w, bt);
    k_gemm<<<dim3(8, 8, SPLITK), 256, 0, stream>>>(feat, bt, prt);
    k_lnreduce<<<1024, 256, 0, stream>>>(prt, proj_b, ln_g, ln_b, pos, out);
}

// Round 3
// 259.755 us; speedup vs baseline: 1.0553x; 1.0553x over previous
//
#include <hip/hip_runtime.h>
#include <hip/hip_bf16.h>

typedef unsigned short u16;
typedef unsigned int u32;
typedef __attribute__((ext_vector_type(4))) float f32x4;
typedef __attribute__((ext_vector_type(4))) unsigned int u32x4;
typedef __attribute__((ext_vector_type(8))) short bf16x8;

#define DD 1024
#define BSZ 32
#define MROWS 1024
#define K3 3072
#define SPLITK 4
#define KSPLIT 768
#define BMT 128
#define BKT 64

static __device__ __forceinline__ u16 bf16rne(float f) {
    union { float f; u32 u; } a; a.f = f;
    u32 r = a.u + 0x7fffu + ((a.u >> 16) & 1u);
    return (u16)(r >> 16);
}
static __device__ __forceinline__ u32 packbf2(float a, float b) {
    return (u32)bf16rne(a) | ((u32)bf16rne(b) << 16);
}

// ---------------- kernel 1 (merged): blocks [0,1024): per-32-row stats -> feat bf16
//                                     blocks [1024,1792): proj_w f32 -> Bt bf16 transpose
__global__ __launch_bounds__(512, 1) void k_prep(const float* __restrict__ x,
                                                 const float* __restrict__ w_w,
                                                 const float* __restrict__ w_b,
                                                 u16* __restrict__ feat,
                                                 const float* __restrict__ pw,
                                                 u16* __restrict__ bt) {
    __shared__ float smem[64 * 68];
    const int t = threadIdx.x;
    if (blockIdx.x < 1024) {
        // ---- block stats: one block per 32-row chunk, thread owns cols 2t,2t+1 ----
        const int m = blockIdx.x;
        const int lane = t & 63, wv = t >> 6;
        const float2 wp = *(const float2*)(w_w + 2 * t);
        const float* xb = x + (size_t)m * (BSZ * DD);
        float2 xs[BSZ];
#pragma unroll
        for (int r = 0; r < BSZ; ++r)
            xs[r] = *(const float2*)(xb + (size_t)r * DD + 2 * t);
        // logits: per-row partial dot, 3-level shfl (8-lane groups), 8 partials/wave -> LDS
#pragma unroll
        for (int r = 0; r < BSZ; ++r) {
            float d = xs[r].x * wp.x + xs[r].y * wp.y;
            d += __shfl_xor(d, 1); d += __shfl_xor(d, 2); d += __shfl_xor(d, 4);
            if ((lane & 7) == 0) smem[r * 68 + wv * 8 + (lane >> 3)] = d;
        }
        __syncthreads();
        float* wts = smem + 32 * 68;
        if (t < 32) {   // softmax over the 32 logits
            float s = w_b[0];
            const float* row = smem + t * 68;
#pragma unroll
            for (int j = 0; j < 16; ++j) {
                f32x4 v = *(const f32x4*)(row + 4 * j);
                s += v[0] + v[1] + v[2] + v[3];
            }
            float mx = s;
#pragma unroll
            for (int off = 16; off; off >>= 1) mx = fmaxf(mx, __shfl_xor(mx, off, 32));
            float e = __expf(s - mx);
            float se = e;
#pragma unroll
            for (int off = 16; off; off >>= 1) se += __shfl_xor(se, off, 32);
            wts[t] = e / se;
        }
        __syncthreads();
        float wmx = 0.f, wmy = 0.f, m2x = 0.f, m2y = 0.f, mxx = -3.4e38f, mxy = -3.4e38f;
#pragma unroll
        for (int r = 0; r < BSZ; ++r) {
            float w = wts[r];
            float2 v = xs[r];
            wmx += w * v.x; wmy += w * v.y;
            m2x += w * v.x * v.x; m2y += w * v.y * v.y;
            mxx = fmaxf(mxx, v.x); mxy = fmaxf(mxy, v.y);
        }
        float sdx = sqrtf(fmaxf(m2x - wmx * wmx, 0.f) + 1e-8f);
        float sdy = sqrtf(fmaxf(m2y - wmy * wmy, 0.f) + 1e-8f);
        u32* fr = (u32*)(feat + (size_t)m * K3);   // [mn | sd | mx], 512 u32 each
        fr[t] = packbf2(wmx, wmy);
        fr[512 + t] = packbf2(sdx, sdy);
        fr[1024 + t] = packbf2(mxx, mxy);
    } else {
        // ---- transpose+cast: 64x64 f32 tile of proj_w -> bf16 Bt[n][k] ----
        const int bid = blockIdx.x - 1024;   // 0..767
        const int bk = bid >> 4;             // 0..47 (K blocks of 64)
        const int bn = bid & 15;             // 0..15 (N blocks of 64)
        const int r = t >> 3;                // 0..63
        const int c0 = (t & 7) * 8;          // 0..56
        const float* src = pw + (size_t)(bk * 64 + r) * DD + bn * 64 + c0;
        float4 v0 = *(const float4*)(src);
        float4 v1 = *(const float4*)(src + 4);
        *(float4*)(smem + r * 68 + c0) = v0;
        *(float4*)(smem + r * 68 + c0 + 4) = v1;
        __syncthreads();
        const int n = t >> 3;                // output row within tile, 0..63
        const int kq = (t & 7) * 8;          // 0..56
        u32x4 o;
#pragma unroll
        for (int j = 0; j < 4; ++j)
            o[j] = packbf2(smem[(kq + 2 * j) * 68 + n], smem[(kq + 2 * j + 1) * 68 + n]);
        *(u32x4*)(bt + (size_t)(bn * 64 + n) * K3 + bk * 64 + kq) = o;
    }
}

// ---------------- kernel 2: C_partial[z] = feat[:, zK:(z+1)K] @ Bt[:, zK:(z+1)K]^T ----------------
// 128x128 tile, BK=64, 4 waves x 4x4 16x16x32 frags, split-K=4,
// global_load_lds w=16, XOR-swizzled global source + swizzled LDS read (rule #21).
__global__ __launch_bounds__(256) void k_gemm(const u16* __restrict__ A, const u16* __restrict__ Bt,
                                              float* __restrict__ part) {
    __shared__ u16 As[2][BMT * BKT];
    __shared__ u16 Bs[2][BMT * BKT];
    const int t = threadIdx.x;
    const int m0 = blockIdx.x * BMT;
    const int n0 = blockIdx.y * BMT;
    const int z = blockIdx.z;
    const int k0 = z * KSPLIT;

    const int lane = t & 63;
    const int wv = t >> 6;
    const int wm = (wv >> 1) * 64;
    const int wn = (wv & 1) * 64;
    const int l15 = lane & 15;
    const int lh = lane >> 4;

    const int srow = t >> 3;
    const int scb = (t & 7) * 16;
    const int gcb = scb ^ ((srow & 7) << 4);
    const u16* gAr = A + (size_t)(m0 + srow) * K3 + (gcb >> 1) + k0;
    const u16* gBr = Bt + (size_t)(n0 + srow) * K3 + (gcb >> 1) + k0;
    const int ldsBase = (t & ~63) * 8;   // wave-uniform LDS base (u16 elems)

    f32x4 acc[4][4] = {};

#define STAGE(buf, kEl)                                                                            \
    {                                                                                              \
        _Pragma("unroll") for (int j = 0; j < 4; ++j) {                                            \
            __builtin_amdgcn_global_load_lds(                                                      \
                (__attribute__((address_space(1))) void*)(gAr + (kEl) + (size_t)j * 32 * K3),      \
                (__attribute__((address_space(3))) void*)&As[buf][j * 2048 + ldsBase], 16, 0, 0);  \
            __builtin_amdgcn_global_load_lds(                                                      \
                (__attribute__((address_space(1))) void*)(gBr + (kEl) + (size_t)j * 32 * K3),      \
                (__attribute__((address_space(3))) void*)&Bs[buf][j * 2048 + ldsBase], 16, 0, 0);  \
        }                                                                                          \
    }
#define LDIDX(row, cb) ((((row)*128) + (((cb) ^ (((row)&7) << 4)))) >> 1)

    STAGE(0, 0)
    __syncthreads();
    int cur = 0;
    for (int it = 0; it < KSPLIT / BKT; ++it) {   // 12 iters
        if (it < KSPLIT / BKT - 1) STAGE(cur ^ 1, (it + 1) * BKT)
#pragma unroll
        for (int kk = 0; kk < 2; ++kk) {
            bf16x8 af[4], bfr[4];
            const int cb = kk * 64 + lh * 16;
#pragma unroll
            for (int mi = 0; mi < 4; ++mi)
                af[mi] = *(const bf16x8*)&As[cur][LDIDX(wm + mi * 16 + l15, cb)];
#pragma unroll
            for (int ni = 0; ni < 4; ++ni)
                bfr[ni] = *(const bf16x8*)&Bs[cur][LDIDX(wn + ni * 16 + l15, cb)];
#pragma unroll
            for (int mi = 0; mi < 4; ++mi)
#pragma unroll
                for (int ni = 0; ni < 4; ++ni)
                    acc[mi][ni] =
                        __builtin_amdgcn_mfma_f32_16x16x32_bf16(af[mi], bfr[ni], acc[mi][ni], 0, 0, 0);
        }
        __syncthreads();   // drains vmcnt (next-tile stage) + lgkm; 2-phase pipeline
        cur ^= 1;
    }

    // C/D map: col = lane&15, row = (lane>>4)*4 + reg  [measured m89/m91]
    float* pz = part + (size_t)z * MROWS * DD;
#pragma unroll
    for (int mi = 0; mi < 4; ++mi) {
#pragma unroll
        for (int r = 0; r < 4; ++r) {
            const int gm = m0 + wm + mi * 16 + lh * 4 + r;
            float* rp = pz + (size_t)gm * DD + n0 + wn + l15;
#pragma unroll
            for (int ni = 0; ni < 4; ++ni) rp[ni * 16] = acc[mi][ni][r];
        }
    }
#undef STAGE
#undef LDIDX
}

// ---------------- kernel 3: sum split-K partials + bias + LayerNorm + pos ----------------
__global__ void k_lnreduce(const float* __restrict__ part, const float* __restrict__ proj_b,
                           const float* __restrict__ ln_g, const float* __restrict__ ln_b,
                           const float* __restrict__ pos, float* __restrict__ out) {
    const int m = blockIdx.x;      // 0..1023
    const int t = threadIdx.x;     // 256
    const int c = 4 * t;
    const int lane = t & 63, wv = t >> 6;
    f32x4 h = {};
#pragma unroll
    for (int s = 0; s < SPLITK; ++s)
        h += *(const f32x4*)(part + ((size_t)s * MROWS + m) * DD + c);
    h += *(const f32x4*)(proj_b + c);
    float sm = h[0] + h[1] + h[2] + h[3];
    float sq = h[0] * h[0] + h[1] * h[1] + h[2] * h[2] + h[3] * h[3];
#pragma unroll
    for (int off = 32; off; off >>= 1) { sm += __shfl_xor(sm, off); sq += __shfl_xor(sq, off); }
    __shared__ float rs[4], rq[4];
    if (lane == 0) { rs[wv] = sm; rq[wv] = sq; }
    __syncthreads();
    const float S = rs[0] + rs[1] + rs[2] + rs[3];
    const float Q = rq[0] + rq[1] + rq[2] + rq[3];
    const float mu = S * (1.f / 1024.f);
    const float var = Q * (1.f / 1024.f) - mu * mu;
    const float rstd = rsqrtf(var + 1e-5f);
    const f32x4 g = *(const f32x4*)(ln_g + c);
    const f32x4 b = *(const f32x4*)(ln_b + c);
    const f32x4 p = *(const f32x4*)(pos + (size_t)(m & 255) * DD + c);
    f32x4 o;
#pragma unroll
    for (int i = 0; i < 4; ++i) o[i] = (h[i] - mu) * rstd * g[i] + b[i] + p[i];
    *(f32x4*)(out + (size_t)m * DD + c) = o;
}

extern "C" void kernel_launch(void* const* d_in, const int* in_sizes, int n_in,
                              void* d_out, int out_size, void* d_ws, size_t ws_size,
                              hipStream_t stream) {
    const float* x      = (const float*)d_in[0];
    const float* w_w    = (const float*)d_in[1];
    const float* w_b    = (const float*)d_in[2];
    const float* proj_w = (const float*)d_in[3];
    const float* proj_b = (const float*)d_in[4];
    const float* ln_g   = (const float*)d_in[5];
    const float* ln_b   = (const float*)d_in[6];
    const float* pos    = (const float*)d_in[7];
    float* out = (float*)d_out;

    char* ws = (char*)d_ws;
    u16* feat  = (u16*)ws;                      // 1024*3072*2 = 6 MiB
    u16* bt    = (u16*)(ws + 6291456);          // 1024*3072*2 = 6 MiB
    float* prt = (float*)(ws + 12582912);       // 4*1024*1024*4 = 16 MiB

    k_prep<<<1792, 512, 0, stream>>>(x, w_w, w_b, feat, proj_w, bt);
    k_gemm<<<dim3(8, 8, SPLITK), 256, 0, stream>>>(feat, bt, prt);
    k_lnreduce<<<1024, 256, 0, stream>>>(prt, proj_b, ln_g, ln_b, pos, out);
}